// Round 2
// 68.655 us; speedup vs baseline: 1.0481x; 1.0481x over previous
//
#include <hip/hip_runtime.h>

// Grouped conv: x (1,48,56,56) f32, w (24,96,7) f32, groups=2.
// y[o,h,wo] = sum_{i<24,k<7} x[24g+i, h, wo+k-3] * w[i, o%96, k]   (pad 3 on W)
// out[o,h,:] = y[o, (h - shift) mod 56, :]   (jnp.roll along H)
//
// Layout: block = 128 threads (2 waves) = 4 output channels x 4 rows x 56 cols.
//   wave wid handles oc pair (obase + 2*wid, +1); lane = (rl = lane>>4, c4 = lane&15).
//   Each lane owns 4 aligned cols [4*c4 .. 4*c4+3] of row (blockIdx.y*4 + rl).
//   Per input channel: 3 aligned float4 loads (cols 4c4-4..4c4+7, clamped in-row),
//   56 FMAs (7 taps x 4 cols x 2 oc). Weights staged in LDS, b128 broadcast reads.
// (Resubmit of round-0 kernel: previous bench failed on container acquisition,
//  kernel never executed.)

#define Hh 56
#define Wd 56
#define HWsz (Hh * Wd)
#define CI 24
#define KW 7
#define OCB 4   // output channels per block

__global__ __launch_bounds__(128) void conv7_roll_kernel(
    const float* __restrict__ x,
    const float* __restrict__ w,
    const int* __restrict__ shift_p,
    float* __restrict__ out)
{
    const int tid  = threadIdx.x;
    const int wid  = tid >> 6;          // 0..1  -> oc pair
    const int lane = tid & 63;
    const int rl   = lane >> 4;         // 0..3  row within 4-row group
    const int c4r  = lane & 15;         // 0..15 (14,15 inactive)
    const int c4   = c4r < 13 ? c4r : 13;   // clamp inactive lanes to a safe strip

    const int obase = blockIdx.x * OCB;     // 0,4,...,188 (never straddles group)
    const int g     = obase / 96;
    const int ocb96 = obase - g * 96;

    // Stage weights: wl[oc_l][ci][8] (k=7 is pad)
    __shared__ __align__(16) float wl[OCB * CI * 8];
    for (int t = tid; t < OCB * CI * 8; t += 128) {
        const int oc_l = t / (CI * 8);
        const int rem  = t - oc_l * (CI * 8);
        const int ci   = rem >> 3;
        const int k    = rem & 7;
        wl[t] = (k < KW) ? w[ci * (96 * KW) + (ocb96 + oc_l) * KW + k] : 0.0f;
    }
    __syncthreads();

    const int shift = shift_p[0];
    const int h_out = blockIdx.y * 4 + rl;
    int hi = (h_out - shift) % Hh;
    if (hi < 0) hi += Hh;

    // All three load pointers stay inside row hi: cols [0,56) after clamping.
    const float* xp = x + g * (CI * HWsz) + hi * Wd + c4 * 4;
    const float* lp = xp + (c4 > 0  ? -4 : 0);
    const float* rp = xp + (c4 < 13 ?  4 : 0);
    const bool lz = (c4 == 0);
    const bool rz = (c4 >= 13);

    const float* wl0 = &wl[(wid * 2    ) * (CI * 8)];
    const float* wl1 = &wl[(wid * 2 + 1) * (CI * 8)];

    float a0[4] = {0.f, 0.f, 0.f, 0.f};
    float a1[4] = {0.f, 0.f, 0.f, 0.f};

    #pragma unroll 4
    for (int ci = 0; ci < CI; ++ci) {
        float4 M = *(const float4*)(xp + ci * HWsz);
        float4 L = *(const float4*)(lp + ci * HWsz);
        float4 R = *(const float4*)(rp + ci * HWsz);
        if (lz) { L.x = 0.f; L.y = 0.f; L.z = 0.f; L.w = 0.f; }
        if (rz) { R.x = 0.f; R.y = 0.f; R.z = 0.f; R.w = 0.f; }
        // Window cols 4c4-4 .. 4c4+7; output col 4c4+j uses xv[1+j+k].
        float xv[12] = {L.x, L.y, L.z, L.w, M.x, M.y, M.z, M.w, R.x, R.y, R.z, R.w};

        float4 wa = *(const float4*)(wl0 + ci * 8);
        float4 wb = *(const float4*)(wl0 + ci * 8 + 4);
        float4 wc = *(const float4*)(wl1 + ci * 8);
        float4 wd = *(const float4*)(wl1 + ci * 8 + 4);
        float w0[7] = {wa.x, wa.y, wa.z, wa.w, wb.x, wb.y, wb.z};
        float w1[7] = {wc.x, wc.y, wc.z, wc.w, wd.x, wd.y, wd.z};

        #pragma unroll
        for (int k = 0; k < KW; ++k) {
            #pragma unroll
            for (int j = 0; j < 4; ++j) {
                a0[j] += xv[1 + j + k] * w0[k];
                a1[j] += xv[1 + j + k] * w1[k];
            }
        }
    }

    if (c4r < 14) {
        const int o0 = obase + wid * 2;
        float* op0 = out + o0 * HWsz + h_out * Wd + c4 * 4;
        float* op1 = op0 + HWsz;
        *(float4*)op0 = make_float4(a0[0], a0[1], a0[2], a0[3]);
        *(float4*)op1 = make_float4(a1[0], a1[1], a1[2], a1[3]);
    }
}

extern "C" void kernel_launch(void* const* d_in, const int* in_sizes, int n_in,
                              void* d_out, int out_size, void* d_ws, size_t ws_size,
                              hipStream_t stream)
{
    const float* x     = (const float*)d_in[0];
    const float* w     = (const float*)d_in[1];
    const int*   shift = (const int*)d_in[2];
    float*       out   = (float*)d_out;

    dim3 grid(48, 14);   // 192/4 oc-groups x 56/4 row-groups
    conv7_roll_kernel<<<grid, 128, 0, stream>>>(x, w, shift, out);
}